// Round 4
// baseline (161.671 us; speedup 1.0000x reference)
//
#include <hip/hip_runtime.h>
#include <math.h>

#define NFFT  1024
#define TIME_ 262144
#define NWIN  1021   // (262144 - 1024)/256 + 1
#define NPAIR 511    // pair p covers windows 2p, 2p+1
#define BATCH 32

typedef float fv4 __attribute__((ext_vector_type(4)));

__device__ __forceinline__ float2 cmul(float2 a, float2 b) {
    return make_float2(fmaf(a.x, b.x, -(a.y * b.y)),
                       fmaf(a.x, b.y,  (a.y * b.x)));
}
__device__ __forceinline__ float2 cconj(float2 a) { return make_float2(a.x, -a.y); }

// Forward 4-point DFT: X[k] = sum_n v[n] * (-i)^(n*k)
__device__ __forceinline__ void dft4(float2 v[4]) {
    float2 a = make_float2(v[0].x + v[2].x, v[0].y + v[2].y);
    float2 b = make_float2(v[0].x - v[2].x, v[0].y - v[2].y);
    float2 c = make_float2(v[1].x + v[3].x, v[1].y + v[3].y);
    float2 d = make_float2(v[1].x - v[3].x, v[1].y - v[3].y);
    v[0] = make_float2(a.x + c.x, a.y + c.y);
    v[2] = make_float2(a.x - c.x, a.y - c.y);
    v[1] = make_float2(b.x + d.y, b.y - d.x);   // b - i*d
    v[3] = make_float2(b.x - d.y, b.y + d.x);   // b + i*d
}

// w[e] = exp(i * e * ang), e = 0..15 (ang negative for forward FFT).
__device__ __forceinline__ void twpows(float ang, float2 w[16]) {
    float s1, c1, s4, c4, s8, c8;
    __sincosf(ang, &s1, &c1);
    __sincosf(4.0f * ang, &s4, &c4);
    __sincosf(8.0f * ang, &s8, &c8);
    float2 w1 = make_float2(c1, s1);
    float2 w4 = make_float2(c4, s4);
    float2 w8 = make_float2(c8, s8);
    w[0]  = make_float2(1.0f, 0.0f);
    w[1]  = w1;
    w[2]  = cmul(w1, w1);
    w[3]  = cmul(w4, cconj(w1));
    w[4]  = w4;
    w[5]  = cmul(w4, w1);
    w[6]  = cmul(w8, cconj(w[2]));
    w[7]  = cmul(w8, cconj(w1));
    w[8]  = w8;
    w[9]  = cmul(w8, w1);
    w[10] = cmul(w8, w[2]);
    w[12] = cmul(w8, w4);
    w[11] = cmul(w[12], cconj(w1));
    w[13] = cmul(w[12], w1);
    w[14] = cmul(w[12], w[2]);
    w[15] = cmul(w[12], w[3]);
}

// o[k] = sum_n v[n] * exp(-2pi i n k / 16), natural order in and out.
__device__ __forceinline__ void dft16(const float2 v[16], float2 o[16]) {
    const float C1 = 0.92387953251128675613f;   // cos(pi/8)
    const float S1 = 0.38268343236508977173f;   // sin(pi/8)
    const float R2 = 0.70710678118654752440f;   // sqrt(2)/2
    float2 c[4][4];                              // c[n1a][k1a]
#pragma unroll
    for (int a = 0; a < 4; ++a) {
        float2 t[4] = { v[a], v[a + 4], v[a + 8], v[a + 12] };
        dft4(t);
#pragma unroll
        for (int k = 0; k < 4; ++k) c[a][k] = t[k];
    }
    c[1][1] = cmul(c[1][1], make_float2( C1, -S1));
    c[1][2] = cmul(c[1][2], make_float2( R2, -R2));
    c[1][3] = cmul(c[1][3], make_float2( S1, -C1));
    c[2][1] = cmul(c[2][1], make_float2( R2, -R2));
    c[2][2] = make_float2(c[2][2].y, -c[2][2].x);          // * W16^4 = -i
    c[2][3] = cmul(c[2][3], make_float2(-R2, -R2));
    c[3][1] = cmul(c[3][1], make_float2( S1, -C1));
    c[3][2] = cmul(c[3][2], make_float2(-R2, -R2));
    c[3][3] = cmul(c[3][3], make_float2(-C1,  S1));        // W16^9 = -W16^1
#pragma unroll
    for (int k1a = 0; k1a < 4; ++k1a) {
        float2 t[4] = { c[0][k1a], c[1][k1a], c[2][k1a], c[3][k1a] };
        dft4(t);
#pragma unroll
        for (int k1b = 0; k1b < 4; ++k1b) o[k1a + 4 * k1b] = t[k1b];
    }
}

// 16 samples (4 float4 chunks) into D[0..15].
__device__ __forceinline__ void load16(float* D, const float* s, int lane) {
#pragma unroll
    for (int c = 0; c < 4; ++c) {
        float4 f = *(const float4*)(s + 4 * lane + 256 * c);
        D[4 * c + 0] = f.x; D[4 * c + 1] = f.y;
        D[4 * c + 2] = f.z; D[4 * c + 3] = f.w;
    }
}
__device__ __forceinline__ void load4tail(float* D, const float* s, int lane, bool v) {
    if (v) {
        float4 f = *(const float4*)(s + 4 * lane + 1024);
        D[16] = f.x; D[17] = f.y; D[18] = f.z; D[19] = f.w;
    } else {
        D[16] = D[17] = D[18] = D[19] = 0.0f;
    }
}

// One 1024-point two-for-one FFT + untangle + nt stores for one (pair, batch).
// Identical math/layout to the verified R3 kernel; see R3 comments for the
// index derivations. z is an opaque runtime 0 (defeats CSE/LICM of the two
// twiddle builds across the two bodies, which would cost +64 live VGPRs).
__device__ __forceinline__ void fft_body(float2* __restrict__ L,
                                         const float* __restrict__ Ls,
                                         float* __restrict__ oa,
                                         float* __restrict__ ob,
                                         bool wbv, int lane, int z)
{
    // ---- stage 1: radix-4 over n0 (stride 256), write A[n2][k0][n1] ----
#pragma unroll
    for (int t = 0; t < 4; ++t) {
        float2 v[4];
#pragma unroll
        for (int n0 = 0; n0 < 4; ++n0)
            v[n0] = make_float2(Ls[4 * n0 + t], Ls[4 * n0 + 4 + t]);
        dft4(v);
        const int idx = 4 * lane + t;
        const int n2 = idx & 15, n1 = idx >> 4;
        const int wb = 64 * n2 + (n1 ^ ((n2 & 7) << 1));
#pragma unroll
        for (int k0 = 0; k0 < 4; ++k0)
            L[wb + 16 * k0] = v[k0];
    }

    // ---- exchange 1 read: lane owns (n2 = lane&15, k0 = lane>>4) ----
    const int n2r = lane & 15, k0r = lane >> 4;
    float2 Av[16];
    {
        const int rb = 64 * n2r + 16 * k0r;
        const int m  = (n2r & 7) << 1;
#pragma unroll
        for (int u = 0; u < 8; ++u) {
            float4 q = *(const float4*)&L[rb + ((2 * u) ^ m)];
            Av[2 * u]     = make_float2(q.x, q.y);
            Av[2 * u + 1] = make_float2(q.z, q.w);
        }
    }

    // ---- stage 2: twiddle W64^(n1*k0), DFT16 over n1 -> k1 ----
    float2 w[16];
    twpows(-0.0981747704246810387f * (float)(k0r | z), w);   // -2pi/64 * k0
#pragma unroll
    for (int i = 1; i < 16; ++i) Av[i] = cmul(Av[i], w[i]);
    float2 Bq[16];
    dft16(Av, Bq);

    // ---- exchange 2 write: B[n2][k0][k1] -> slot 16*(k0+4k1) + (n2 ^ swz) ----
#pragma unroll
    for (int k1 = 0; k1 < 16; ++k1) {
        const int lp = k0r + 4 * k1;
        L[16 * lp + (n2r ^ ((lp & 7) << 1))] = Bq[k1];
    }

    // ---- exchange 2 read: lane' = k0 + 4*k1 = lane, 16 consecutive n2 ----
    float2 Cv[16];
    {
        const int rb2 = 16 * lane;
        const int m2  = (lane & 7) << 1;
#pragma unroll
        for (int u = 0; u < 8; ++u) {
            float4 q = *(const float4*)&L[rb2 + ((2 * u) ^ m2)];
            Cv[2 * u]     = make_float2(q.x, q.y);
            Cv[2 * u + 1] = make_float2(q.z, q.w);
        }
    }

    // ---- stage 3: twiddle W1024^(n2*lane'), DFT16 over n2 -> k2 ----
    twpows(-0.00613592315154256491f * (float)(lane | z), w); // -2pi/1024 * lane'
#pragma unroll
    for (int i = 1; i < 16; ++i) Cv[i] = cmul(Cv[i], w[i]);
    float2 Sv[16];                                     // Sv[k2] = S[lane + 64*k2]
    dft16(Cv, Sv);

    // ---- park S[k] (k = lane + 64*k2) into granule-swizzled layout ----
    {
        const int pb = ((lane >> 2) ^ (lane & 3)) + ((lane & 3) << 6);
#pragma unroll
        for (int k2 = 0; k2 < 16; ++k2)
            L[pb + 16 * (k2 & 3) + 256 * (k2 >> 2)] = Sv[k2];
    }

    // ---- epilogue: lane owns k = 4*lane + 256g + j; untangle + nt stores ----
    const int Ll  = lane & 15,      Lh  = lane >> 4;
    const int ML  = 63 - lane;
    const int MLl = ML & 15,        MLh = ML >> 4;
    const int Lm0 = (64 - lane) & 63;
    const int m0b = (Lm0 & 15) + 16 * (Lm0 >> 4);
#pragma unroll
    for (int g = 0; g < 4; ++g) {
        float2 So[4], Sm[4];
#pragma unroll
        for (int j = 0; j < 4; ++j)
            So[j] = L[(Ll ^ j) + 16 * Lh + 64 * j + 256 * g];
#pragma unroll
        for (int jp = 1; jp < 4; ++jp)      // Sm[4-jp] = mirror elem for j=4-jp
            Sm[4 - jp] = L[(MLl ^ jp) + 16 * MLh + 64 * jp + 256 * (3 - g)];
        const int gm0 = lane ? (3 - g) : ((4 - g) & 3);
        Sm[0] = L[m0b + 256 * gm0];

        fv4 av, bv;
        av.x = 0.5f * (So[0].x + Sm[0].x);  bv.x = 0.5f * (So[0].y + Sm[0].y);
        av.y = 0.5f * (So[1].x + Sm[1].x);  bv.y = 0.5f * (So[1].y + Sm[1].y);
        av.z = 0.5f * (So[2].x + Sm[2].x);  bv.z = 0.5f * (So[2].y + Sm[2].y);
        av.w = 0.5f * (So[3].x + Sm[3].x);  bv.w = 0.5f * (So[3].y + Sm[3].y);

        // Nontemporal: output is write-once, never re-read -> bypass L2 so the
        // 134 MB write stream doesn't evict the L2-resident input.
        __builtin_nontemporal_store(av, (fv4*)(oa + 256 * g));
        if (wbv) __builtin_nontemporal_store(bv, (fv4*)(ob + 256 * g));
    }
}

// One 64-lane wave handles one window-pair for TWO batches (D=2 pipeline):
// all 10 float4 loads are issued up front, so batch-1's global-load latency
// hides under batch-0's ~2000-cycle FFT. Zero __syncthreads (wave-synchronous
// DS ordering, HW-validated rounds 1-3; body-1 stage-1 writes cannot pass
// body-0 epilogue reads: same-wave DS ops execute in issue order).
__global__ __launch_bounds__(256) void StridedFourier_kernel(
    const float* __restrict__ x, float* __restrict__ out)
{
    __shared__ __align__(16) float2 lds[4][NFFT];

    const int tid  = threadIdx.x;
    const int lane = tid & 63;
    const int wid  = tid >> 6;

    // XCD-aware swizzle (bijective on 128; linear%8 == bx%8 since gridDim.x=128).
    int bx = blockIdx.x;                 // 0..127
    bx = ((bx & 7) << 4) | (bx >> 3);
    const int p = bx * 4 + wid;          // window pair
    if (p >= NPAIR) return;              // one idle wave in one block column
    const int bat0 = blockIdx.y * 2;     // batches {bat0, bat0+1}
    const bool wbv = (2 * p + 1) < NWIN; // last pair is a singleton

    const float* src = x + (size_t)bat0 * TIME_ + (size_t)p * 512;
    float2* L = lds[wid];

    // ---- issue ALL global loads for both batches up front ----
    float A[20], Pn[20];
    load16(A,  src,          lane);
    load16(Pn, src + TIME_,  lane);
    load4tail(A,  src,         lane, wbv);
    load4tail(Pn, src + TIME_, lane, wbv);

    // Opaque zeros (distinct SSA values; volatile asm is never CSE'd).
    int z0 = 0; asm volatile("" : "+v"(z0));
    int z1 = 0; asm volatile("" : "+v"(z1));

    const long long obase = ((long long)bat0 * NWIN + 2LL * p) * NFFT;
    float* oa0 = out + obase + 4 * lane;
    fft_body(L, A, oa0, oa0 + NFFT, wbv, lane, z0);

    float* oa1 = oa0 + (long long)NWIN * NFFT;   // next batch, same pair
    fft_body(L, Pn, oa1, oa1 + NFFT, wbv, lane, z1);
}

extern "C" void kernel_launch(void* const* d_in, const int* in_sizes, int n_in,
                              void* d_out, int out_size, void* d_ws, size_t ws_size,
                              hipStream_t stream) {
    const float* x = (const float*)d_in[0];
    float* out = (float*)d_out;
    dim3 grid(128, 16);                  // 128 pair-blocks x 16 batch-groups (D=2)
    StridedFourier_kernel<<<grid, 256, 0, stream>>>(x, out);
}

// Round 5
// 154.482 us; speedup vs baseline: 1.0465x; 1.0465x over previous
//
#include <hip/hip_runtime.h>
#include <math.h>

#define NFFT  1024
#define TIME_ 262144
#define NWIN  1021   // (262144 - 1024)/256 + 1
#define NPAIR 511    // pair p covers windows 2p, 2p+1
#define BATCH 32

__device__ __forceinline__ float2 cmul(float2 a, float2 b) {
    return make_float2(fmaf(a.x, b.x, -(a.y * b.y)),
                       fmaf(a.x, b.y,  (a.y * b.x)));
}
__device__ __forceinline__ float2 cconj(float2 a) { return make_float2(a.x, -a.y); }

// Forward 4-point DFT: X[k] = sum_n v[n] * (-i)^(n*k)
__device__ __forceinline__ void dft4(float2 v[4]) {
    float2 a = make_float2(v[0].x + v[2].x, v[0].y + v[2].y);
    float2 b = make_float2(v[0].x - v[2].x, v[0].y - v[2].y);
    float2 c = make_float2(v[1].x + v[3].x, v[1].y + v[3].y);
    float2 d = make_float2(v[1].x - v[3].x, v[1].y - v[3].y);
    v[0] = make_float2(a.x + c.x, a.y + c.y);
    v[2] = make_float2(a.x - c.x, a.y - c.y);
    v[1] = make_float2(b.x + d.y, b.y - d.x);   // b - i*d
    v[3] = make_float2(b.x - d.y, b.y + d.x);   // b + i*d
}

// Twiddle-fused DFT16: o[k] = sum_n (v[n] * w^n) * exp(-2pi i n k / 16),
// w = exp(i*ang). Instead of a 16-entry table (32 live VGPRs), carry 6
// complex twiddles (12 VGPRs): w1..w3 (=w^a) and w4,w8,w12 (=W^k, W=w^4),
// and fold v[a+4k] * (w^a * W^k) into the first radix-4 pass.
// Product trees mirror the old table (w3 = w4*conj(w1), w12 = w8*w4).
__device__ __forceinline__ void dft16tw(const float2 v[16], float2 o[16],
                                        float2 w1, float2 w2, float2 w3,
                                        float2 w4, float2 w8, float2 w12) {
    const float C1 = 0.92387953251128675613f;   // cos(pi/8)
    const float S1 = 0.38268343236508977173f;   // sin(pi/8)
    const float R2 = 0.70710678118654752440f;   // sqrt(2)/2
    float2 c[4][4];                              // c[n1a][k1a]
    {   // column a = 0: twiddles are W^k directly
        float2 t[4] = { v[0], cmul(v[4], w4), cmul(v[8], w8), cmul(v[12], w12) };
        dft4(t);
#pragma unroll
        for (int k = 0; k < 4; ++k) c[0][k] = t[k];
    }
    const float2 wa3[3] = { w1, w2, w3 };
#pragma unroll
    for (int a = 1; a < 4; ++a) {
        const float2 wa = wa3[a - 1];
        const float2 p1 = cmul(wa, w4);
        const float2 p2 = cmul(wa, w8);
        const float2 p3 = cmul(wa, w12);
        float2 t[4] = { cmul(v[a], wa), cmul(v[a + 4], p1),
                        cmul(v[a + 8], p2), cmul(v[a + 12], p3) };
        dft4(t);
#pragma unroll
        for (int k = 0; k < 4; ++k) c[a][k] = t[k];
    }
    // c[n1a][k1a] *= W16^(n1a*k1a)
    c[1][1] = cmul(c[1][1], make_float2( C1, -S1));
    c[1][2] = cmul(c[1][2], make_float2( R2, -R2));
    c[1][3] = cmul(c[1][3], make_float2( S1, -C1));
    c[2][1] = cmul(c[2][1], make_float2( R2, -R2));
    c[2][2] = make_float2(c[2][2].y, -c[2][2].x);          // * W16^4 = -i
    c[2][3] = cmul(c[2][3], make_float2(-R2, -R2));
    c[3][1] = cmul(c[3][1], make_float2( S1, -C1));
    c[3][2] = cmul(c[3][2], make_float2(-R2, -R2));
    c[3][3] = cmul(c[3][3], make_float2(-C1,  S1));        // W16^9 = -W16^1
#pragma unroll
    for (int k1a = 0; k1a < 4; ++k1a) {
        float2 t[4] = { c[0][k1a], c[1][k1a], c[2][k1a], c[3][k1a] };
        dft4(t);
#pragma unroll
        for (int k1b = 0; k1b < 4; ++k1b) o[k1a + 4 * k1b] = t[k1b];
    }
}

// One 64-lane wave computes one window-pair via the two-for-one complex FFT:
//   s[n] = a[n] + i*b[n],  S = FFT1024(s),
//   Re A[k] = (S[k].x + S[-k].x)/2,  Re B[k] = (S[k].y + S[-k].y)/2.
// FFT1024 = radix-4 (regs) x DFT16 (regs) x DFT16 (regs), swizzled LDS
// exchanges, ZERO __syncthreads (wave-synchronous; DS ops execute in issue
// order within a wave — HW-validated rounds 1-4).
// n = n2 + 16*n1 + 256*n0, k = k0 + 4*k1 + 64*k2, lane' = k0 + 4*k1.
//
// R5 theme: occupancy. Per-CU pipe inventory (64 bodies/CU): VALU ~17us,
// LDS ~18us, HBM ~24.5us — observed 39us means poor overlap at ~4 waves/SIMD.
// Register diet (fused twiddles: 32->12 live VGPRs) + __launch_bounds__(256,5)
// targets 5 blocks/CU (LDS: 5 x 32KB = 160KB = exactly CU capacity).
__global__ __launch_bounds__(256, 5) void StridedFourier_kernel(
    const float* __restrict__ x, float* __restrict__ out)
{
    __shared__ __align__(16) float2 lds[4][NFFT];

    const int tid  = threadIdx.x;
    const int lane = tid & 63;
    const int wid  = tid >> 6;

    // XCD-aware swizzle (bijective on 128).
    int bx = blockIdx.x;                 // 0..127
    bx = ((bx & 7) << 4) | (bx >> 3);
    const int p = bx * 4 + wid;          // window pair
    if (p >= NPAIR) return;              // one idle wave in one block column
    const int bat = blockIdx.y;
    const bool wbv = (2 * p + 1) < NWIN; // last pair is a singleton

    const float* src = x + (size_t)bat * TIME_ + (size_t)p * 512;
    float2* L = lds[wid];

    // ---- global load: 5 float4 per lane (20 samples), fully coalesced ----
    float Ls[20];
#pragma unroll
    for (int c = 0; c < 4; ++c) {
        float4 f = *(const float4*)(src + 4 * lane + 256 * c);
        Ls[4 * c + 0] = f.x; Ls[4 * c + 1] = f.y;
        Ls[4 * c + 2] = f.z; Ls[4 * c + 3] = f.w;
    }
    if (wbv) {
        float4 f = *(const float4*)(src + 4 * lane + 1024);
        Ls[16] = f.x; Ls[17] = f.y; Ls[18] = f.z; Ls[19] = f.w;
    } else {
        Ls[16] = Ls[17] = Ls[18] = Ls[19] = 0.0f;
    }

    // ---- stage 1: radix-4 over n0 (stride 256), write A[n2][k0][n1] ----
#pragma unroll
    for (int t = 0; t < 4; ++t) {
        float2 v[4];
#pragma unroll
        for (int n0 = 0; n0 < 4; ++n0)
            v[n0] = make_float2(Ls[4 * n0 + t], Ls[4 * n0 + 4 + t]);
        dft4(v);
        const int idx = 4 * lane + t;
        const int n2 = idx & 15, n1 = idx >> 4;
        const int wb = 64 * n2 + (n1 ^ ((n2 & 7) << 1));
#pragma unroll
        for (int k0 = 0; k0 < 4; ++k0)
            L[wb + 16 * k0] = v[k0];
    }

    // ---- exchange 1 read: lane owns (n2 = lane&15, k0 = lane>>4) ----
    const int n2r = lane & 15, k0r = lane >> 4;
    float2 Av[16];
    {
        const int rb = 64 * n2r + 16 * k0r;
        const int m  = (n2r & 7) << 1;
#pragma unroll
        for (int u = 0; u < 8; ++u) {
            float4 q = *(const float4*)&L[rb + ((2 * u) ^ m)];
            Av[2 * u]     = make_float2(q.x, q.y);
            Av[2 * u + 1] = make_float2(q.z, q.w);
        }
    }

    // ---- stage 2: twiddle W64^(n1*k0) fused into DFT16 over n1 -> k1 ----
    float2 Bq[16];
    {
        const float ang = -0.0981747704246810387f * (float)k0r;  // -2pi/64 * k0
        float s1, c1, s4, c4, s8, c8;
        __sincosf(ang, &s1, &c1);
        __sincosf(4.0f * ang, &s4, &c4);
        __sincosf(8.0f * ang, &s8, &c8);
        const float2 w1 = make_float2(c1, s1);
        const float2 w4 = make_float2(c4, s4);
        const float2 w8 = make_float2(c8, s8);
        dft16tw(Av, Bq, w1, cmul(w1, w1), cmul(w4, cconj(w1)),
                w4, w8, cmul(w8, w4));
    }

    // ---- exchange 2 write: B[n2][k0][k1] -> slot 16*(k0+4k1) + (n2 ^ swz) ----
#pragma unroll
    for (int k1 = 0; k1 < 16; ++k1) {
        const int lp = k0r + 4 * k1;
        L[16 * lp + (n2r ^ ((lp & 7) << 1))] = Bq[k1];
    }

    // ---- exchange 2 read: lane' = k0 + 4*k1 = lane, 16 consecutive n2 ----
    float2 Cv[16];
    {
        const int rb2 = 16 * lane;
        const int m2  = (lane & 7) << 1;
#pragma unroll
        for (int u = 0; u < 8; ++u) {
            float4 q = *(const float4*)&L[rb2 + ((2 * u) ^ m2)];
            Cv[2 * u]     = make_float2(q.x, q.y);
            Cv[2 * u + 1] = make_float2(q.z, q.w);
        }
    }

    // ---- stage 3: twiddle W1024^(n2*lane') fused into DFT16 over n2 -> k2 ----
    float2 Sv[16];                                     // Sv[k2] = S[lane + 64*k2]
    {
        const float ang = -0.00613592315154256491f * (float)lane; // -2pi/1024 * l'
        float s1, c1, s4, c4, s8, c8;
        __sincosf(ang, &s1, &c1);
        __sincosf(4.0f * ang, &s4, &c4);
        __sincosf(8.0f * ang, &s8, &c8);
        const float2 w1 = make_float2(c1, s1);
        const float2 w4 = make_float2(c4, s4);
        const float2 w8 = make_float2(c8, s8);
        dft16tw(Cv, Sv, w1, cmul(w1, w1), cmul(w4, cconj(w1)),
                w4, w8, cmul(w8, w4));
    }

    // ---- park S[k] (k = lane + 64*k2) into granule-swizzled layout ----
    // k -> j = lane&3, Lo = (lane>>2) + 16*(k2&3), g = k2>>2
    // slot = ((Lo&15)^j) + 16*(Lo>>4) + 64*j + 256*g
    {
        const int pb = ((lane >> 2) ^ (lane & 3)) + ((lane & 3) << 6);
#pragma unroll
        for (int k2 = 0; k2 < 16; ++k2)
            L[pb + 16 * (k2 & 3) + 256 * (k2 >> 2)] = Sv[k2];
    }

    // ---- epilogue: lane owns k = 4*lane + 256g + j; mirror of k is
    // granule (63-lane, 3-g) element 4-j for j=1..3, and for j=0 the bin
    // at granule ((64-lane)&63, ...) element 0.
    const int Ll  = lane & 15,      Lh  = lane >> 4;
    const int ML  = 63 - lane;
    const int MLl = ML & 15,        MLh = ML >> 4;
    const int Lm0 = (64 - lane) & 63;
    const int m0b = (Lm0 & 15) + 16 * (Lm0 >> 4);
    const long long cbase = ((long long)bat * NWIN + 2LL * p) * NFFT;
    float* oa = out + cbase + 4 * lane;
    float* ob = oa + NFFT;
#pragma unroll
    for (int g = 0; g < 4; ++g) {
        float2 So[4], Sm[4];
#pragma unroll
        for (int j = 0; j < 4; ++j)
            So[j] = L[(Ll ^ j) + 16 * Lh + 64 * j + 256 * g];
#pragma unroll
        for (int jp = 1; jp < 4; ++jp)      // Sm[4-jp] = mirror elem for j=4-jp
            Sm[4 - jp] = L[(MLl ^ jp) + 16 * MLh + 64 * jp + 256 * (3 - g)];
        const int gm0 = lane ? (3 - g) : ((4 - g) & 3);
        Sm[0] = L[m0b + 256 * gm0];

        float4 av, bv;
        av.x = 0.5f * (So[0].x + Sm[0].x);  bv.x = 0.5f * (So[0].y + Sm[0].y);
        av.y = 0.5f * (So[1].x + Sm[1].x);  bv.y = 0.5f * (So[1].y + Sm[1].y);
        av.z = 0.5f * (So[2].x + Sm[2].x);  bv.z = 0.5f * (So[2].y + Sm[2].y);
        av.w = 0.5f * (So[3].x + Sm[3].x);  bv.w = 0.5f * (So[3].y + Sm[3].y);

        *(float4*)(oa + 256 * g) = av;              // 64 lanes x 16B contiguous
        if (wbv) *(float4*)(ob + 256 * g) = bv;     // = 1KB full-line wave store
    }
}

extern "C" void kernel_launch(void* const* d_in, const int* in_sizes, int n_in,
                              void* d_out, int out_size, void* d_ws, size_t ws_size,
                              hipStream_t stream) {
    const float* x = (const float*)d_in[0];
    float* out = (float*)d_out;
    dim3 grid(128, BATCH);               // 128 pair-blocks x 32 batches
    StridedFourier_kernel<<<grid, 256, 0, stream>>>(x, out);
}